// Round 2
// baseline (90.852 us; speedup 1.0000x reference)
//
#include <hip/hip_runtime.h>
#include <stdint.h>

// Problem geometry (fixed by setup_inputs): x0 [32,64,64,256] f32 one-hot.
#define N_PIX     131072u
#define KDIM      256u

__device__ __forceinline__ uint32_t rotl32(uint32_t v, int r) {
  return (v << r) | (v >> (32 - r));
}

// Threefry-2x32-20 with key (0,1) == jax.random.key(1).
// Returns XOR of the two output words (JAX partitionable 32-bit combine).
__device__ __forceinline__ uint32_t threefry_xor_01(uint32_t c0, uint32_t c1) {
  const uint32_t ks0 = 0u;
  const uint32_t ks1 = 1u;
  const uint32_t ks2 = 0x1BD11BDAu ^ ks0 ^ ks1;  // 0x1BD11BDB
  uint32_t x0 = c0 + ks0;
  uint32_t x1 = c1 + ks1;
#define TF_R(r) { x0 += x1; x1 = rotl32(x1, (r)); x1 ^= x0; }
  TF_R(13) TF_R(15) TF_R(26) TF_R(6)
  x0 += ks1; x1 += ks2 + 1u;
  TF_R(17) TF_R(29) TF_R(16) TF_R(24)
  x0 += ks2; x1 += ks0 + 2u;
  TF_R(13) TF_R(15) TF_R(26) TF_R(6)
  x0 += ks0; x1 += ks1 + 3u;
  TF_R(17) TF_R(29) TF_R(16) TF_R(24)
  x0 += ks1; x1 += ks2 + 4u;
  TF_R(13) TF_R(15) TF_R(26) TF_R(6)
  x0 += ks2; x1 += ks0 + 5u;
#undef TF_R
  return x0 ^ x1;
}

// bits -> jax.random.uniform(minval=1e-9, maxval=1.0) value
__device__ __forceinline__ float bits_to_uniform(uint32_t bits) {
  float f = __uint_as_float((bits >> 9) | 0x3F800000u) - 1.0f;  // [0,1)
  // JAX: floats * (maxval-minval) + minval ; (1.0f - 1e-9f) == 1.0f exactly
  float u = f * 1.0f + 1e-9f;
  return fmaxf(1e-9f, u);
}

// Kernel A: abar = prod_{i<t}(1 - beta[i])  -> ws[0]
__global__ void abar_kernel(const float* __restrict__ beta,
                            const int* __restrict__ t_ptr,
                            float* __restrict__ ws) {
  const int t = t_ptr[0];
  const int lane = threadIdx.x;  // 64 threads
  float p = 1.0f;
  for (int i = lane; i < t; i += 64) p *= (1.0f - beta[i]);
  for (int off = 32; off; off >>= 1) p *= __shfl_down(p, off);
  if (lane == 0) ws[0] = p;
}

// Kernel B: one pixel per block (256 channels), 128 threads x 2 channels.
__global__ __launch_bounds__(128) void
diffusion_sample_kernel(const float2* __restrict__ x0,
                        const float* __restrict__ abar_p,
                        float2* __restrict__ out) {
  const int tid = threadIdx.x;        // 0..127
  const uint32_t P = blockIdx.x;      // pixel
  const uint32_t j0 = P * KDIM + 2u * (uint32_t)tid;  // flat element index

  const float abar = abar_p[0];
  const float poff = (1.0f - abar) * (1.0f / 256.0f);

  // partitionable threefry: counter = (hi32(j)=0, lo32(j)=j)
  const uint32_t bits0 = threefry_xor_01(0u, j0);
  const uint32_t bits1 = threefry_xor_01(0u, j0 + 1u);

  const float u0 = bits_to_uniform(bits0);
  const float u1 = bits_to_uniform(bits1);
  // exp(gumbel) = exp(-log(-log u)) = 1/(-log u)
  const float w0 = -1.0f / logf(u0);
  const float w1 = -1.0f / logf(u1);

  const float2 xv = x0[(size_t)P * 128u + (size_t)tid];
  const float n0 = fmaf(xv.x, abar, poff) * w0;
  const float n1 = fmaf(xv.y, abar, poff) * w1;

  // block-wide sum over 256 channels (2 waves x 2 elems)
  float r = n0 + n1;
  for (int off = 32; off; off >>= 1) r += __shfl_down(r, off);
  __shared__ float sh[2];
  if ((tid & 63) == 0) sh[tid >> 6] = r;
  __syncthreads();
  const float sinv = 1.0f / (sh[0] + sh[1]);

  out[(size_t)P * 128u + (size_t)tid] = make_float2(n0 * sinv, n1 * sinv);
}

extern "C" void kernel_launch(void* const* d_in, const int* in_sizes, int n_in,
                              void* d_out, int out_size, void* d_ws, size_t ws_size,
                              hipStream_t stream) {
  const float* x0   = (const float*)d_in[0];
  const float* beta = (const float*)d_in[1];
  const int*   t    = (const int*)d_in[2];
  float* out = (float*)d_out;
  float* ws  = (float*)d_ws;

  abar_kernel<<<1, 64, 0, stream>>>(beta, t, ws);
  diffusion_sample_kernel<<<N_PIX, 128, 0, stream>>>(
      (const float2*)x0, ws, (float2*)out);
}

// Round 4
// 78.820 us; speedup vs baseline: 1.1527x; 1.1527x over previous
//
#include <hip/hip_runtime.h>
#include <stdint.h>

// Problem geometry (fixed by setup_inputs): x0 [32,64,64,256] f32 one-hot.
#define N_PIX     131072u
#define KDIM      256u

typedef float f32x4 __attribute__((ext_vector_type(4)));

__device__ __forceinline__ uint32_t rotl32(uint32_t v, int r) {
  return (v << r) | (v >> (32 - r));   // compiles to v_alignbit_b32
}

// Threefry-2x32-20 with key (0,1) == jax.random.key(1); counter = (0, c1).
// Returns XOR of the two output words (JAX partitionable 32-bit combine).
__device__ __forceinline__ uint32_t threefry_xor_01(uint32_t c1) {
  const uint32_t ks0 = 0u;
  const uint32_t ks1 = 1u;
  const uint32_t ks2 = 0x1BD11BDBu;  // 0x1BD11BDA ^ 0 ^ 1
  uint32_t x0 = 0u + ks0;            // c0 = 0 for all elements (n < 2^32)
  uint32_t x1 = c1 + ks1;
#define TF_R(r) { x0 += x1; x1 = rotl32(x1, (r)); x1 ^= x0; }
  TF_R(13) TF_R(15) TF_R(26) TF_R(6)
  x0 += ks1; x1 += ks2 + 1u;
  TF_R(17) TF_R(29) TF_R(16) TF_R(24)
  x0 += ks2; x1 += ks0 + 2u;
  TF_R(13) TF_R(15) TF_R(26) TF_R(6)
  x0 += ks0; x1 += ks1 + 3u;
  TF_R(17) TF_R(29) TF_R(16) TF_R(24)
  x0 += ks1; x1 += ks2 + 4u;
  TF_R(13) TF_R(15) TF_R(26) TF_R(6)
  x0 += ks2; x1 += ks0 + 5u;
#undef TF_R
  return x0 ^ x1;
}

// bits -> u = jax.random.uniform(1e-9, 1.0) -> exp(gumbel) = 1/(-ln u)
// Fast path: ln u = ln2 * log2(u); w = (-1/ln2) * rcp(log2 u).
__device__ __forceinline__ float gumbel_weight(uint32_t bits) {
  float f = __uint_as_float((bits >> 9) | 0x3F800000u) - 1.0f;  // [0,1)
  float u = fmaxf(1e-9f, f + 1e-9f);       // JAX: *(maxval-minval)+minval, clamped
  float L = __log2f(u);                    // v_log_f32, L in [-29.9, ~-6e-8)
  L = fminf(L, -1.0e-20f);                 // guard: never 0/-0 -> w stays finite
  return -1.44269504088896340736f * __builtin_amdgcn_rcpf(L);
}

// Kernel A: abar = prod_{i<t}(1 - beta[i])  -> ws[0]
__global__ void abar_kernel(const float* __restrict__ beta,
                            const int* __restrict__ t_ptr,
                            float* __restrict__ ws) {
  const int t = t_ptr[0];
  const int lane = threadIdx.x;  // 64 threads
  float p = 1.0f;
  for (int i = lane; i < t; i += 64) p *= (1.0f - beta[i]);
  for (int off = 32; off; off >>= 1) p *= __shfl_down(p, off);
  if (lane == 0) ws[0] = p;
}

// Kernel B: 256 threads = 4 waves; each wave owns one pixel (256 channels),
// each lane 4 consecutive channels (float4). Wave-only butterfly reduction.
__global__ __launch_bounds__(256) void
diffusion_sample_kernel(const f32x4* __restrict__ x0,
                        const float* __restrict__ abar_p,
                        f32x4* __restrict__ out) {
  const int lane = threadIdx.x & 63;
  const int wave = threadIdx.x >> 6;
  const uint32_t P = blockIdx.x * 4u + (uint32_t)wave;   // pixel
  const uint32_t j0 = P * KDIM + (uint32_t)lane * 4u;    // flat element index

  const float abar = abar_p[0];
  const float poff = (1.0f - abar) * (1.0f / 256.0f);

  // 4 independent hash chains (ILP)
  const uint32_t b0 = threefry_xor_01(j0);
  const uint32_t b1 = threefry_xor_01(j0 + 1u);
  const uint32_t b2 = threefry_xor_01(j0 + 2u);
  const uint32_t b3 = threefry_xor_01(j0 + 3u);

  const size_t v = (size_t)P * 64u + (size_t)lane;
  const f32x4 xv = x0[v];

  const float n0 = fmaf(xv.x, abar, poff) * gumbel_weight(b0);
  const float n1 = fmaf(xv.y, abar, poff) * gumbel_weight(b1);
  const float n2 = fmaf(xv.z, abar, poff) * gumbel_weight(b2);
  const float n3 = fmaf(xv.w, abar, poff) * gumbel_weight(b3);

  // sum over the wave's 256 channels (butterfly: every lane gets the total)
  float r = (n0 + n1) + (n2 + n3);
  #pragma unroll
  for (int off = 32; off; off >>= 1) r += __shfl_xor(r, off);
  const float sinv = __builtin_amdgcn_rcpf(r);

  f32x4 o;
  o.x = n0 * sinv; o.y = n1 * sinv; o.z = n2 * sinv; o.w = n3 * sinv;
  __builtin_nontemporal_store(o, &out[v]);  // don't evict x0 from L2/L3
}

extern "C" void kernel_launch(void* const* d_in, const int* in_sizes, int n_in,
                              void* d_out, int out_size, void* d_ws, size_t ws_size,
                              hipStream_t stream) {
  const float* x0   = (const float*)d_in[0];
  const float* beta = (const float*)d_in[1];
  const int*   t    = (const int*)d_in[2];
  float* out = (float*)d_out;
  float* ws  = (float*)d_ws;

  abar_kernel<<<1, 64, 0, stream>>>(beta, t, ws);
  diffusion_sample_kernel<<<N_PIX / 4u, 256, 0, stream>>>(
      (const f32x4*)x0, ws, (f32x4*)out);
}

// Round 5
// 74.683 us; speedup vs baseline: 1.2165x; 1.0554x over previous
//
#include <hip/hip_runtime.h>
#include <stdint.h>

// Problem geometry (fixed by setup_inputs): x0 [32,64,64,256] f32 one-hot.
#define N_PIX     131072u
#define KDIM      256u

typedef float f32x4 __attribute__((ext_vector_type(4)));

// Single-instruction rotate: v_alignbit_b32 computes ((a:b) >> c);
// with a==b==v and c = 32-r this is rotl(v, r).
__device__ __forceinline__ uint32_t rotl(uint32_t v, int r) {
  return __builtin_amdgcn_alignbit(v, v, 32u - (uint32_t)r);
}

// Threefry-2x32-20 with key (0,1) == jax.random.key(1); counter = (0, c1).
// Returns XOR of the two output words (JAX partitionable 32-bit combine) —
// bit-exactness confirmed (round-2/4 absmax 4.9e-4 pass).
__device__ __forceinline__ uint32_t threefry_xor_01(uint32_t c1) {
  const uint32_t ks0 = 0u;
  const uint32_t ks1 = 1u;
  const uint32_t ks2 = 0x1BD11BDBu;  // 0x1BD11BDA ^ 0 ^ 1
  uint32_t x0 = 0u + ks0;            // c0 = 0 for all elements (n < 2^32)
  uint32_t x1 = c1 + ks1;
#define TF_R(r) { x0 += x1; x1 = rotl(x1, (r)); x1 ^= x0; }
  TF_R(13) TF_R(15) TF_R(26) TF_R(6)
  x0 += ks1; x1 += ks2 + 1u;
  TF_R(17) TF_R(29) TF_R(16) TF_R(24)
  x0 += ks2; x1 += ks0 + 2u;
  TF_R(13) TF_R(15) TF_R(26) TF_R(6)
  x0 += ks0; x1 += ks1 + 3u;
  TF_R(17) TF_R(29) TF_R(16) TF_R(24)
  x0 += ks1; x1 += ks2 + 4u;
  TF_R(13) TF_R(15) TF_R(26) TF_R(6)
  x0 += ks2; x1 += ks0 + 5u;
#undef TF_R
  return x0 ^ x1;
}

// bits -> log2(u) where u = jax.random.uniform(1e-9, 1.0).
// fmax dropped: f >= 0 so f+1e-9 >= 1e-9 always.
// fmin guard dropped: u <= 1-2^-24 -> log2(u) <= -8.6e-8 (normal, v_log_f32
// 1-ulp error cannot produce -0), so rcp stays finite.
__device__ __forceinline__ float log2_u(uint32_t bits) {
  float f = __uint_as_float((bits >> 9) | 0x3F800000u) - 1.0f;  // [0,1)
  return __log2f(f + 1e-9f);
}

// Kernel A: abar = prod_{i<t}(1 - beta[i])  -> ws[0]
__global__ void abar_kernel(const float* __restrict__ beta,
                            const int* __restrict__ t_ptr,
                            float* __restrict__ ws) {
  const int t = t_ptr[0];
  const int lane = threadIdx.x;  // 64 threads
  float p = 1.0f;
  for (int i = lane; i < t; i += 64) p *= (1.0f - beta[i]);
  for (int off = 32; off; off >>= 1) p *= __shfl_down(p, off);
  if (lane == 0) ws[0] = p;
}

// Kernel B: 256 threads = 4 waves; each wave owns one pixel (256 channels),
// each lane 4 consecutive channels (float4). Wave-only butterfly reduction.
// out_j = m_j / sum(m)  with  m_j = p_j * rcp(log2 u_j)   (p_j > 0, log2 < 0;
// the ln2 constants cancel in the ratio, sign cancels too).
__global__ __launch_bounds__(256) void
diffusion_sample_kernel(const f32x4* __restrict__ x0,
                        const float* __restrict__ abar_p,
                        f32x4* __restrict__ out) {
  const int lane = threadIdx.x & 63;
  const int wave = threadIdx.x >> 6;
  const uint32_t P = blockIdx.x * 4u + (uint32_t)wave;   // pixel
  const uint32_t j0 = P * KDIM + (uint32_t)lane * 4u;    // flat element index

  const float abar = abar_p[0];
  const float poff = (1.0f - abar) * (1.0f / 256.0f);

  // 4 independent hash chains (ILP)
  const uint32_t b0 = threefry_xor_01(j0);
  const uint32_t b1 = threefry_xor_01(j0 + 1u);
  const uint32_t b2 = threefry_xor_01(j0 + 2u);
  const uint32_t b3 = threefry_xor_01(j0 + 3u);

  const size_t v = (size_t)P * 64u + (size_t)lane;
  const f32x4 xv = x0[v];

  const float m0 = fmaf(xv.x, abar, poff) * __builtin_amdgcn_rcpf(log2_u(b0));
  const float m1 = fmaf(xv.y, abar, poff) * __builtin_amdgcn_rcpf(log2_u(b1));
  const float m2 = fmaf(xv.z, abar, poff) * __builtin_amdgcn_rcpf(log2_u(b2));
  const float m3 = fmaf(xv.w, abar, poff) * __builtin_amdgcn_rcpf(log2_u(b3));

  // sum over the wave's 256 channels; ds_swizzle xor-butterfly (single LDS
  // inst per stage, no VALU address calc), then cross-32 via shfl_xor.
  float r = (m0 + m1) + (m2 + m3);
#define SWZ_XOR(k) \
  r += __int_as_float(__builtin_amdgcn_ds_swizzle(__float_as_int(r), ((k) << 10) | 0x1F))
  SWZ_XOR(1); SWZ_XOR(2); SWZ_XOR(4); SWZ_XOR(8); SWZ_XOR(16);
#undef SWZ_XOR
  r += __shfl_xor(r, 32);
  const float sinv = __builtin_amdgcn_rcpf(r);

  f32x4 o;
  o.x = m0 * sinv; o.y = m1 * sinv; o.z = m2 * sinv; o.w = m3 * sinv;
  __builtin_nontemporal_store(o, &out[v]);
}

extern "C" void kernel_launch(void* const* d_in, const int* in_sizes, int n_in,
                              void* d_out, int out_size, void* d_ws, size_t ws_size,
                              hipStream_t stream) {
  const float* x0   = (const float*)d_in[0];
  const float* beta = (const float*)d_in[1];
  const int*   t    = (const int*)d_in[2];
  float* out = (float*)d_out;
  float* ws  = (float*)d_ws;

  abar_kernel<<<1, 64, 0, stream>>>(beta, t, ws);
  diffusion_sample_kernel<<<N_PIX / 4u, 256, 0, stream>>>(
      (const f32x4*)x0, ws, (f32x4*)out);
}

// Round 6
// 73.669 us; speedup vs baseline: 1.2333x; 1.0138x over previous
//
#include <hip/hip_runtime.h>
#include <stdint.h>

// Problem geometry (fixed by setup_inputs): x0 [32,64,64,256] f32 one-hot.
#define N_PIX     131072u
#define KDIM      256u

typedef float f32x4 __attribute__((ext_vector_type(4)));

// Single-instruction rotate: v_alignbit_b32((v:v) >> (32-r)) == rotl(v,r).
__device__ __forceinline__ uint32_t rotl(uint32_t v, int r) {
  return __builtin_amdgcn_alignbit(v, v, 32u - (uint32_t)r);
}

// Threefry-2x32-20 with key (0,1) == jax.random.key(1); counter = (0, c1).
// Returns XOR of the two output words (JAX partitionable 32-bit combine) —
// bit-exactness confirmed by rounds 2/4/5 passing at absmax 4.9e-4.
__device__ __forceinline__ uint32_t threefry_xor_01(uint32_t c1) {
  const uint32_t ks0 = 0u;
  const uint32_t ks1 = 1u;
  const uint32_t ks2 = 0x1BD11BDBu;  // 0x1BD11BDA ^ 0 ^ 1
  uint32_t x0 = 0u + ks0;            // c0 = 0 for all elements (n < 2^32)
  uint32_t x1 = c1 + ks1;
#define TF_R(r) { x0 += x1; x1 = rotl(x1, (r)); x1 ^= x0; }
  TF_R(13) TF_R(15) TF_R(26) TF_R(6)
  x0 += ks1; x1 += ks2 + 1u;
  TF_R(17) TF_R(29) TF_R(16) TF_R(24)
  x0 += ks2; x1 += ks0 + 2u;
  TF_R(13) TF_R(15) TF_R(26) TF_R(6)
  x0 += ks0; x1 += ks1 + 3u;
  TF_R(17) TF_R(29) TF_R(16) TF_R(24)
  x0 += ks1; x1 += ks2 + 4u;
  TF_R(13) TF_R(15) TF_R(26) TF_R(6)
  x0 += ks2; x1 += ks0 + 5u;
#undef TF_R
  return x0 ^ x1;
}

// bits -> m-weight factor rcp(log2(f)), f = JAX's exact 23-bit uniform in [0,1).
// (+1e-9 dropped: u need not be bit-exact, only the hash bits. f==0 gives
//  log2->-inf, rcp->-0, m->-0: softmax entry +0 vs ref ~6e-5, well in tol.)
// All m's are NEGATIVE (log2<0); the sign and ln2 constants cancel in m/sum(m).
__device__ __forceinline__ float inv_log2_u(uint32_t bits) {
  float f = __uint_as_float((bits >> 9) | 0x3F800000u) - 1.0f;  // [0,1)
  return __builtin_amdgcn_rcpf(__log2f(f));
}

// Kernel A: abar = prod_{i<t}(1 - beta[i])  -> ws[0]
__global__ void abar_kernel(const float* __restrict__ beta,
                            const int* __restrict__ t_ptr,
                            float* __restrict__ ws) {
  const int t = t_ptr[0];
  const int lane = threadIdx.x;  // 64 threads
  float p = 1.0f;
  for (int i = lane; i < t; i += 64) p *= (1.0f - beta[i]);
  for (int off = 32; off; off >>= 1) p *= __shfl_down(p, off);
  if (lane == 0) ws[0] = p;
}

// Kernel B: 256 threads = 4 waves. Each wave handles TWO pixels: lanes 0-31
// -> pixel 2W, lanes 32-63 -> pixel 2W+1. Each lane: 8 channels (two f32x4
// slots l and l+32 of its pixel -> fully dense coalesced loads), 8 hash
// chains (ILP), 3+5-stage reduction entirely within 32-lane halves
// (ds_swizzle and_mask=0x1F operates per-32-lane group -> no cross-32 shfl).
__global__ __launch_bounds__(256) void
diffusion_sample_kernel(const f32x4* __restrict__ x0,
                        const float* __restrict__ abar_p,
                        f32x4* __restrict__ out) {
  const int lane = threadIdx.x & 63;
  const int half = lane >> 5;           // which pixel of the wave's pair
  const int l    = lane & 31;           // lane within the 32-lane half
  const int wave = threadIdx.x >> 6;
  const uint32_t W = blockIdx.x * 4u + (uint32_t)wave;   // wave id = pixel pair
  const uint32_t P = W * 2u + (uint32_t)half;            // pixel

  const float abar = abar_p[0];
  const float poff = (1.0f - abar) * (1.0f / 256.0f);

  // element indices: channels 4l..4l+3 and 128+4l..128+4l+3 of pixel P
  const uint32_t jA = P * KDIM + (uint32_t)l * 4u;
  const uint32_t jB = jA + 128u;

  // 8 independent hash chains
  const uint32_t a0 = threefry_xor_01(jA);
  const uint32_t a1 = threefry_xor_01(jA + 1u);
  const uint32_t a2 = threefry_xor_01(jA + 2u);
  const uint32_t a3 = threefry_xor_01(jA + 3u);
  const uint32_t b0 = threefry_xor_01(jB);
  const uint32_t b1 = threefry_xor_01(jB + 1u);
  const uint32_t b2 = threefry_xor_01(jB + 2u);
  const uint32_t b3 = threefry_xor_01(jB + 3u);

  const size_t v0 = (size_t)P * 64u + (size_t)l;   // f32x4 slot, channels 4l..
  const size_t v1 = v0 + 32u;                      // channels 128+4l..
  const f32x4 xa = x0[v0];
  const f32x4 xb = x0[v1];

  const float mA0 = fmaf(xa.x, abar, poff) * inv_log2_u(a0);
  const float mA1 = fmaf(xa.y, abar, poff) * inv_log2_u(a1);
  const float mA2 = fmaf(xa.z, abar, poff) * inv_log2_u(a2);
  const float mA3 = fmaf(xa.w, abar, poff) * inv_log2_u(a3);
  const float mB0 = fmaf(xb.x, abar, poff) * inv_log2_u(b0);
  const float mB1 = fmaf(xb.y, abar, poff) * inv_log2_u(b1);
  const float mB2 = fmaf(xb.z, abar, poff) * inv_log2_u(b2);
  const float mB3 = fmaf(xb.w, abar, poff) * inv_log2_u(b3);

  // pixel sum: local 7 adds + 5-stage xor-butterfly within the 32-lane half
  float r = ((mA0 + mA1) + (mA2 + mA3)) + ((mB0 + mB1) + (mB2 + mB3));
#define SWZ_XOR(k) \
  r += __int_as_float(__builtin_amdgcn_ds_swizzle(__float_as_int(r), ((k) << 10) | 0x1F))
  SWZ_XOR(1); SWZ_XOR(2); SWZ_XOR(4); SWZ_XOR(8); SWZ_XOR(16);
#undef SWZ_XOR
  const float sinv = __builtin_amdgcn_rcpf(r);

  f32x4 oa, ob;
  oa.x = mA0 * sinv; oa.y = mA1 * sinv; oa.z = mA2 * sinv; oa.w = mA3 * sinv;
  ob.x = mB0 * sinv; ob.y = mB1 * sinv; ob.z = mB2 * sinv; ob.w = mB3 * sinv;
  __builtin_nontemporal_store(oa, &out[v0]);
  __builtin_nontemporal_store(ob, &out[v1]);
}

extern "C" void kernel_launch(void* const* d_in, const int* in_sizes, int n_in,
                              void* d_out, int out_size, void* d_ws, size_t ws_size,
                              hipStream_t stream) {
  const float* x0   = (const float*)d_in[0];
  const float* beta = (const float*)d_in[1];
  const int*   t    = (const int*)d_in[2];
  float* out = (float*)d_out;
  float* ws  = (float*)d_ws;

  abar_kernel<<<1, 64, 0, stream>>>(beta, t, ws);
  // N_PIX/2 pixel-pairs, 4 pairs per block
  diffusion_sample_kernel<<<N_PIX / 8u, 256, 0, stream>>>(
      (const f32x4*)x0, ws, (f32x4*)out);
}